// Round 5
// baseline (306.587 us; speedup 1.0000x reference)
//
#include <hip/hip_runtime.h>
#include <hip/hip_bf16.h>

#define N_NODES 100000
#define N_EDGES 1600000
#define N_AGENTS 1000

#define SCAN_BLOCK 256
#define N_SCAN_BLOCKS ((N_NODES + SCAN_BLOCK - 1) / SCAN_BLOCK)   // 391
#define AGG_BLOCKS 2048

typedef short s16x8 __attribute__((ext_vector_type(8)));
typedef float f32x4 __attribute__((ext_vector_type(4)));

// float -> bf16 round-to-nearest-even
__device__ __forceinline__ unsigned short f2bf(float f) {
    unsigned u = __float_as_uint(f);
    u += 0x7fffu + ((u >> 16) & 1u);
    return (unsigned short)(u >> 16);
}
__device__ __forceinline__ float bflo(unsigned u) { return __uint_as_float(u << 16); }
__device__ __forceinline__ float bfhi(unsigned u) { return __uint_as_float(u & 0xffff0000u); }

// ---------------- degree + per-edge rank: 4 edges/thread for atomic ILP ----------------
__global__ void degree_rank_kernel(const int* __restrict__ dst, int* __restrict__ cnt,
                                   int* __restrict__ rank) {
    int base = (blockIdx.x * blockDim.x + threadIdx.x) * 4;
    if (base + 3 < N_EDGES) {
        int4 d = *(const int4*)(dst + base);
        int r0 = atomicAdd(&cnt[d.x], 1);
        int r1 = atomicAdd(&cnt[d.y], 1);
        int r2 = atomicAdd(&cnt[d.z], 1);
        int r3 = atomicAdd(&cnt[d.w], 1);
        *(int4*)(rank + base) = make_int4(r0, r1, r2, r3);
    } else if (base < N_EDGES) {
        for (int e = base; e < N_EDGES; e++) rank[e] = atomicAdd(&cnt[dst[e]], 1);
    }
}

// ---------------- scan pass 1 ----------------
__global__ void scan1_kernel(const int* __restrict__ cnt, int* __restrict__ rowptr,
                             int* __restrict__ bsum) {
    __shared__ int tmp[SCAN_BLOCK];
    int i = blockIdx.x * SCAN_BLOCK + threadIdx.x;
    int v = (i < N_NODES) ? cnt[i] : 0;
    tmp[threadIdx.x] = v;
    __syncthreads();
    for (int off = 1; off < SCAN_BLOCK; off <<= 1) {
        int u = (threadIdx.x >= off) ? tmp[threadIdx.x - off] : 0;
        __syncthreads();
        tmp[threadIdx.x] += u;
        __syncthreads();
    }
    if (i < N_NODES) rowptr[i] = tmp[threadIdx.x] - v;
    if (threadIdx.x == SCAN_BLOCK - 1) bsum[blockIdx.x] = tmp[SCAN_BLOCK - 1];
}

// ---------------- scan pass 2 ----------------
__global__ void scan2_kernel(int* __restrict__ bsum) {
    __shared__ int tmp[512];
    int t = threadIdx.x;
    int v = (t < N_SCAN_BLOCKS) ? bsum[t] : 0;
    tmp[t] = v;
    __syncthreads();
    for (int off = 1; off < 512; off <<= 1) {
        int u = (t >= off) ? tmp[t - off] : 0;
        __syncthreads();
        tmp[t] += u;
        __syncthreads();
    }
    if (t < N_SCAN_BLOCKS) bsum[t] = tmp[t] - v;
}

// ---------------- scan pass 3: add offsets; emit inv-degree ----------------
__global__ void scan3_kernel(const int* __restrict__ cnt, int* __restrict__ rowptr,
                             const int* __restrict__ bsum, float* __restrict__ inv) {
    int i = blockIdx.x * SCAN_BLOCK + threadIdx.x;
    if (i == 0) rowptr[N_NODES] = N_EDGES;
    if (i >= N_NODES) return;
    rowptr[i] += bsum[blockIdx.x];
    inv[i] = 1.0f / fmaxf((float)cnt[i], 1.0f);
}

// ---------------- permute edges into CSR order: 4 edges/thread ----------------
__global__ void permute_kernel(const int* __restrict__ src, const int* __restrict__ dst,
                               const int* __restrict__ rank, const int* __restrict__ rowptr,
                               int* __restrict__ esrc) {
    int base = (blockIdx.x * blockDim.x + threadIdx.x) * 4;
    if (base >= N_EDGES) return;
    int4 s = *(const int4*)(src + base);
    int4 d = *(const int4*)(dst + base);
    int4 r = *(const int4*)(rank + base);
    esrc[rowptr[d.x] + r.x] = s.x;
    esrc[rowptr[d.y] + r.y] = s.y;
    esrc[rowptr[d.z] + r.z] = s.z;
    esrc[rowptr[d.w] + r.w] = s.w;
}

// ---------------- convert x (fp32) -> bf16 ----------------
__global__ void convert_x_kernel(const float* __restrict__ x, unsigned short* __restrict__ xb) {
    int i = blockIdx.x * blockDim.x + threadIdx.x;        // one float4 per thread
    if (i >= N_NODES * 32 / 4) return;
    float4 v = ((const float4*)x)[i];
    ushort4 o = make_ushort4(f2bf(v.x), f2bf(v.y), f2bf(v.z), f2bf(v.w));
    ((ushort4*)xb)[i] = o;
}

// ---------------- convert weights -> bf16, stacked [64 k][32 n] per layer ----------------
__global__ void prep_w_kernel(const float* __restrict__ Wl1, const float* __restrict__ Wr1,
                              const float* __restrict__ Wl2, const float* __restrict__ Wr2,
                              const float* __restrict__ Wl3, const float* __restrict__ Wr3,
                              unsigned short* __restrict__ Wcat) {
    int gid = blockIdx.x * blockDim.x + threadIdx.x;
    if (gid >= 3 * 2048) return;
    int L = gid >> 11, idx = gid & 2047;
    int k = idx >> 5, n = idx & 31;
    const float* Wl = (L == 0) ? Wl1 : (L == 1) ? Wl2 : Wl3;
    const float* Wr = (L == 0) ? Wr1 : (L == 1) ? Wr2 : Wr3;
    float v = (k < 32) ? Wl[k * 32 + n] : Wr[(k - 32) * 32 + n];
    Wcat[gid] = f2bf(v);
}

// ---------------- aggregate: mean of bf16 neighbor rows (fp32 acc) -> bf16 mean ----------------
// One wave per node; lane = (slot 0..15)*4 + (q 0..3); 16 neighbors in flight,
// each 64 B row gathered by 4 lanes as uint4 (16 B = 8 bf16 channels).
__global__ __launch_bounds__(256) void aggregate_kernel(
    const int* __restrict__ rowptr, const int* __restrict__ esrc,
    const float* __restrict__ inv, const unsigned short* __restrict__ hb,
    unsigned short* __restrict__ meanb, int n_nodes)
{
    int tid = threadIdx.x;
    int lane = tid & 63, wave = tid >> 6;
    int slot = lane >> 2, q = lane & 3;
    int stride = gridDim.x * 4;
    for (int node = blockIdx.x * 4 + wave; node < n_nodes; node += stride) {
        int beg = rowptr[node], end = rowptr[node + 1];
        float a0 = 0.f, a1 = 0.f, a2 = 0.f, a3 = 0.f;
        float a4 = 0.f, a5 = 0.f, a6 = 0.f, a7 = 0.f;
        for (int j = beg + slot; j < end; j += 16) {
            int s = esrc[j];
            uint4 u = *(const uint4*)(hb + s * 32 + q * 8);
            a0 += bflo(u.x); a1 += bfhi(u.x);
            a2 += bflo(u.y); a3 += bfhi(u.y);
            a4 += bflo(u.z); a5 += bfhi(u.z);
            a6 += bflo(u.w); a7 += bfhi(u.w);
        }
        #pragma unroll
        for (int m = 4; m <= 32; m <<= 1) {
            a0 += __shfl_xor(a0, m); a1 += __shfl_xor(a1, m);
            a2 += __shfl_xor(a2, m); a3 += __shfl_xor(a3, m);
            a4 += __shfl_xor(a4, m); a5 += __shfl_xor(a5, m);
            a6 += __shfl_xor(a6, m); a7 += __shfl_xor(a7, m);
        }
        if (lane < 4) {   // lane == q: holds channels 8q..8q+7
            float iv = inv[node];
            uint4 o;
            o.x = (unsigned)f2bf(a0 * iv) | ((unsigned)f2bf(a1 * iv) << 16);
            o.y = (unsigned)f2bf(a2 * iv) | ((unsigned)f2bf(a3 * iv) << 16);
            o.z = (unsigned)f2bf(a4 * iv) | ((unsigned)f2bf(a5 * iv) << 16);
            o.w = (unsigned)f2bf(a6 * iv) | ((unsigned)f2bf(a7 * iv) << 16);
            *(uint4*)(meanb + node * 32 + lane * 8) = o;   // 4 lanes x 16B = 64B coalesced
        }
    }
}

// ---------------- dense: out = relu(cat(mean,self) @ Wcat + b) via MFMA ----------------
// Wave computes a 16-node x 32-channel tile: 2 N-tiles x 2 K-steps = 4 MFMAs.
// A layout: A[m=lane&15][k=quad*8+j]; C/D: col=lane&15, row=quad*4+reg.
__global__ __launch_bounds__(256) void dense_kernel(
    const unsigned short* __restrict__ meanb, const unsigned short* __restrict__ selfb,
    const unsigned short* __restrict__ Wcat, const float* __restrict__ bl,
    void* __restrict__ outp, int n_nodes, int out_f32)
{
    int tid = threadIdx.x;
    int lane = tid & 63, wave = tid >> 6;
    int l15 = lane & 15, quad = lane >> 4;

    // B frags: B[k][n], lane holds n=lane&15 (+16*nt), k=quad*8+j (+32*kt)
    s16x8 bf[2][2];
    #pragma unroll
    for (int kt = 0; kt < 2; kt++)
        #pragma unroll
        for (int nt = 0; nt < 2; nt++)
            #pragma unroll
            for (int j = 0; j < 8; j++) {
                int k = kt * 32 + quad * 8 + j;
                bf[kt][nt][j] = (short)Wcat[k * 32 + l15 + nt * 16];
            }
    float bias0 = bl[l15], bias1 = bl[l15 + 16];

    int ntiles = (n_nodes + 15) >> 4;
    for (int tile = blockIdx.x * 4 + wave; tile < ntiles; tile += gridDim.x * 4) {
        int node = tile * 16 + l15;
        int na = min(node, n_nodes - 1);
        s16x8 am = *(const s16x8*)(meanb + na * 32 + quad * 8);
        s16x8 as = *(const s16x8*)(selfb + na * 32 + quad * 8);
        f32x4 acc0 = {0.f, 0.f, 0.f, 0.f};
        f32x4 acc1 = {0.f, 0.f, 0.f, 0.f};
        acc0 = __builtin_amdgcn_mfma_f32_16x16x32_bf16(am, bf[0][0], acc0, 0, 0, 0);
        acc0 = __builtin_amdgcn_mfma_f32_16x16x32_bf16(as, bf[1][0], acc0, 0, 0, 0);
        acc1 = __builtin_amdgcn_mfma_f32_16x16x32_bf16(am, bf[0][1], acc1, 0, 0, 0);
        acc1 = __builtin_amdgcn_mfma_f32_16x16x32_bf16(as, bf[1][1], acc1, 0, 0, 0);
        #pragma unroll
        for (int r = 0; r < 4; r++) {
            int onode = tile * 16 + quad * 4 + r;
            if (onode < n_nodes) {
                float v0 = fmaxf(acc0[r] + bias0, 0.f);
                float v1 = fmaxf(acc1[r] + bias1, 0.f);
                if (out_f32) {
                    ((float*)outp)[onode * 32 + l15]      = v0;
                    ((float*)outp)[onode * 32 + l15 + 16] = v1;
                } else {
                    ((unsigned short*)outp)[onode * 32 + l15]      = f2bf(v0);
                    ((unsigned short*)outp)[onode * 32 + l15 + 16] = f2bf(v1);
                }
            }
        }
    }
}

// ---------------- output projection: first 1000 nodes, 32 -> 8 (fp32) ----------------
__global__ void out_proj_kernel(const float* __restrict__ h3,
                                const float* __restrict__ Wout,
                                const float* __restrict__ bout,
                                float* __restrict__ out) {
    __shared__ float sWo[256];
    __shared__ float sbo[8];
    int tid = threadIdx.x;
    sWo[tid] = Wout[tid];
    if (tid < 8) sbo[tid] = bout[tid];
    __syncthreads();
    int node = blockIdx.x * 32 + (tid >> 3);
    int c = tid & 7;
    if (node >= N_AGENTS) return;
    float o = sbo[c];
    const float* hr = h3 + node * 32;
    #pragma unroll
    for (int k = 0; k < 32; k++) o += hr[k] * sWo[(k << 3) + c];
    out[node * 8 + c] = o;
}

extern "C" void kernel_launch(void* const* d_in, const int* in_sizes, int n_in,
                              void* d_out, int out_size, void* d_ws, size_t ws_size,
                              hipStream_t stream) {
    const float* x   = (const float*)d_in[0];
    const int* ei    = (const int*)d_in[1];
    const float* Wl1 = (const float*)d_in[2];
    const float* bl1 = (const float*)d_in[3];
    const float* Wr1 = (const float*)d_in[4];
    const float* Wl2 = (const float*)d_in[5];
    const float* bl2 = (const float*)d_in[6];
    const float* Wr2 = (const float*)d_in[7];
    const float* Wl3 = (const float*)d_in[8];
    const float* bl3 = (const float*)d_in[9];
    const float* Wr3 = (const float*)d_in[10];
    const float* Wout = (const float*)d_in[11];
    const float* bout = (const float*)d_in[12];
    float* out = (float*)d_out;

    const int* src = ei;
    const int* dst = ei + N_EDGES;

    // workspace layout
    char* ws = (char*)d_ws;
    int*   cnt    = (int*)ws;                                  ws += (size_t)N_NODES * 4;
    int*   rowptr = (int*)ws;                                  ws += (size_t)(N_NODES + 8) * 4;
    float* inv    = (float*)ws;                                ws += (size_t)N_NODES * 4;
    int*   bsum   = (int*)ws;                                  ws += 512 * 4;
    int*   esrc   = (int*)ws;                                  ws += (size_t)N_EDGES * 4;
    unsigned short* meanb = (unsigned short*)ws;               ws += (size_t)N_NODES * 32 * 2;
    unsigned short* hXb   = (unsigned short*)ws;               ws += (size_t)N_NODES * 32 * 2;
    unsigned short* hAb   = (unsigned short*)ws;               ws += (size_t)N_NODES * 32 * 2;
    unsigned short* hBb   = (unsigned short*)ws;               ws += (size_t)N_NODES * 32 * 2;
    unsigned short* Wcat  = (unsigned short*)ws;               ws += 3 * 2048 * 2;
    float* h3f    = (float*)ws;                                ws += (size_t)N_AGENTS * 32 * 4;
    int*   rank   = (int*)meanb;   // 6.4MB alias: rank dead before layer-1 aggregate writes meanb

    // ---- input conversion (independent of CSR build) ----
    convert_x_kernel<<<(N_NODES * 32 / 4 + 255) / 256, 256, 0, stream>>>(x, hXb);
    prep_w_kernel<<<24, 256, 0, stream>>>(Wl1, Wr1, Wl2, Wr2, Wl3, Wr3, Wcat);

    // ---- CSR build ----
    hipMemsetAsync(cnt, 0, N_NODES * sizeof(int), stream);
    degree_rank_kernel<<<(N_EDGES / 4 + 255) / 256, 256, 0, stream>>>(dst, cnt, rank);
    scan1_kernel<<<N_SCAN_BLOCKS, SCAN_BLOCK, 0, stream>>>(cnt, rowptr, bsum);
    scan2_kernel<<<1, 512, 0, stream>>>(bsum);
    scan3_kernel<<<N_SCAN_BLOCKS, SCAN_BLOCK, 0, stream>>>(cnt, rowptr, bsum, inv);
    permute_kernel<<<(N_EDGES / 4 + 255) / 256, 256, 0, stream>>>(src, dst, rank, rowptr, esrc);

    // ---- layer 1 ----
    aggregate_kernel<<<AGG_BLOCKS, 256, 0, stream>>>(rowptr, esrc, inv, hXb, meanb, N_NODES);
    dense_kernel<<<512, 256, 0, stream>>>(meanb, hXb, Wcat, bl1, hAb, N_NODES, 0);
    // ---- layer 2 ----
    aggregate_kernel<<<AGG_BLOCKS, 256, 0, stream>>>(rowptr, esrc, inv, hAb, meanb, N_NODES);
    dense_kernel<<<512, 256, 0, stream>>>(meanb, hAb, Wcat + 2048, bl2, hBb, N_NODES, 0);
    // ---- layer 3: only nodes < N_AGENTS needed ----
    aggregate_kernel<<<(N_AGENTS + 3) / 4, 256, 0, stream>>>(rowptr, esrc, inv, hBb, meanb, N_AGENTS);
    dense_kernel<<<16, 256, 0, stream>>>(meanb, hBb, Wcat + 4096, bl3, h3f, N_AGENTS, 1);
    out_proj_kernel<<<(N_AGENTS + 31) / 32, 256, 0, stream>>>(h3f, Wout, bout, out);
}